// Round 15
// baseline (354.258 us; speedup 1.0000x reference)
//
#include <hip/hip_runtime.h>
#include <hip/hip_cooperative_groups.h>

// AP (average precision @ IoU 0.5/0.75) for B=256, N=4000, G=50.
// ONE cooperative mega-kernel: tp -> s1 -> (s2+scatter) -> rank -> pos1 -> ap
// separated by grid.sync(). 256 blocks x 1024 threads = 1 block/CU.
//
// History: R1 pos->LDS (771->439). R2-R4 tp stuck on 1M global hist atomics
// -> zero-global-atomic counting sort. R6 423. R7 rank/wave 260. R8 pos
// split 204. R10 bit-exact divide elimination 191. R11 misc neutral.
// R12/R13 cand->global REGRESSED (at grid==CU-count, LDS<64KB is free).
// R14 NBKT=2048, 187.6. All kernels <44us; ~50-90us = 7-launch overhead +
// grid-starved phases -> R15 fuses everything cooperatively.

#define B_ 256
#define N_ 4000
#define G_ 50
#define M_ (B_ * N_)        // 1,024,000 proposals
#define NL_ (B_ * G_)       // 12,800 labels
#define NBKT 2048
#define KP 16
#define TILE (NL_ / KP)     // 800

#define M0_ 0x1.000001p-1   // 0.5  + 2^-25 (exact decision threshold)
#define M1_ 0x1.800001p-1   // 0.75 + 2^-25

typedef unsigned long long u64;
namespace cg = cooperative_groups;

__device__ __forceinline__ unsigned bucket_of(float c) {
    unsigned b = (unsigned)(c * 2048.0f);
    return b > (NBKT - 1) ? (NBKT - 1) : b;
}

union SharedU {
    struct { float2 gtl[G_]; u64 cand[2][G_][64]; unsigned hls[NBKT]; int lcnt[2]; } tp; // 59.8K
    struct { unsigned sc[4][256]; } s1;                                                  // 4K
    struct { unsigned part[1024]; unsigned baseB[NBKT]; unsigned lofs[NBKT]; } sca;      // 20K
    struct { int tile[TILE]; } pos;                                                      // 3.2K
    struct { int sr[NL_]; float cmax[1024]; double red[1024]; } ap;                      // 63.5K
};

__global__ __launch_bounds__(1024, 4) void mega_kernel(
    const float* __restrict__ seg, const float* __restrict__ gts,
    const float* __restrict__ conf,
    int* __restrict__ tpIdx, int* __restrict__ cnt,
    unsigned short* __restrict__ pbh,
    unsigned* __restrict__ total, unsigned* __restrict__ binStart,
    u64* __restrict__ sKey, int* __restrict__ tpRank,
    int* __restrict__ pcount, float* __restrict__ out)
{
    cg::grid_group grid = cg::this_grid();
    __shared__ SharedU sh;
    const int tid = threadIdx.x, lane = tid & 63, wv = tid >> 6;
    const int blk = blockIdx.x;

    // ================= P0: tp (batch = blk) =================
    {
        const int b = blk;
        #pragma unroll
        for (int k = 0; k < NBKT / 1024; ++k) sh.tp.hls[k * 1024 + tid] = 0u;
        if (tid < G_) sh.tp.gtl[tid] = ((const float2*)gts)[b * G_ + tid];
        if (tid < 2) sh.tp.lcnt[tid] = 0;
        __syncthreads();

        const float* cb = conf + (size_t)b * N_;
        #pragma unroll
        for (int s = 0; s < 4; ++s) {
            int n = s * 1024 + tid;
            if (n < N_) atomicAdd(&sh.tp.hls[bucket_of(cb[n])], 1u);
        }

        const float2* sb = (const float2*)(seg + (size_t)b * (N_ * 2));
        float pmin[4], pmax[4], plen[4];
        #pragma unroll
        for (int s = 0; s < 4; ++s) {
            int n = s * 1024 + tid;
            if (n < N_) { float2 v = sb[n]; pmin[s] = v.x; pmax[s] = v.y; }
            else { pmin[s] = 1e9f; pmax[s] = 1e9f; }
            plen[s] = pmax[s] - pmin[s];
        }
        for (int g = 0; g < G_; ++g) {
            float2 gt = sh.tp.gtl[g];
            float glen = gt.y - gt.x;
            u64 m0[4], m1[4];
            #pragma unroll
            for (int s = 0; s < 4; ++s) {
                float inter = fmaxf(fminf(pmax[s], gt.y) - fmaxf(pmin[s], gt.x), 0.0f);
                float uni = plen[s] + glen - inter;    // f32, ref op order
                double di = (double)inter;             // exact
                double du = (double)uni;               // exact; uni > 0
                m0[s] = __ballot(di > M0_ * du);       // == fl(inter/uni) > 0.5f
                m1[s] = __ballot(di > M1_ * du);       // == fl(inter/uni) > 0.75f
            }
            if (lane == 0) {
                #pragma unroll
                for (int s = 0; s < 4; ++s) {
                    sh.tp.cand[0][g][s * 16 + wv] = m0[s];
                    sh.tp.cand[1][g][s * 16 + wv] = m1[s];
                }
            }
        }
        __syncthreads();

        #pragma unroll
        for (int k = 0; k < NBKT / 1024; ++k) {
            int bin = k * 1024 + tid;
            pbh[(size_t)b * NBKT + bin] = (unsigned short)sh.tp.hls[bin];
        }

        if (wv < 2) {   // greedy, wave per threshold
            const int thr_i = wv;
            u64 used = 0ull;
            for (int g = 0; g < G_; ++g) {
                u64 c = sh.tp.cand[thr_i][g][lane] & ~used;
                u64 ball = __ballot(c != 0ull);
                if (ball) {
                    int fl = __ffsll(ball) - 1;
                    if (lane == fl) used |= (c & (0ull - c));
                }
            }
            int cpop = __popcll(used);
            if (cpop) {
                int j = atomicAdd(&sh.tp.lcnt[thr_i], cpop);
                u64 u = used;
                while (u) {
                    int bit = __ffsll(u) - 1;
                    u &= u - 1;
                    tpIdx[thr_i * NL_ + b * G_ + j++] = b * N_ + lane * 64 + bit;
                }
            }
        }
        __syncthreads();
        if (tid < 2) cnt[tid * B_ + b] = sh.tp.lcnt[tid];
    }
    grid.sync();

    // ================= P1: s1 — 8 bins per block =================
    {
        const int grp = tid >> 8;        // 0..3
        const int b = tid & 255;         // batch index within group
        for (int r = 0; r < 2; ++r) {
            int bin = blk * 8 + r * 4 + grp;
            unsigned v = pbh[(size_t)b * NBKT + bin];
            sh.s1.sc[grp][b] = v;
            __syncthreads();
            for (int off = 1; off < 256; off <<= 1) {
                unsigned add = (b >= off) ? sh.s1.sc[grp][b - off] : 0u;
                __syncthreads();
                sh.s1.sc[grp][b] += add;
                __syncthreads();
            }
            pbh[(size_t)b * NBKT + bin] = (unsigned short)(sh.s1.sc[grp][b] - v);
            if (b == 255) total[bin] = sh.s1.sc[grp][255];
            __syncthreads();
        }
    }
    grid.sync();

    // ================= P2: redundant s2 scan + scatter (batch = blk) =======
    {
        uint2 v2 = ((const uint2*)total)[tid];       // bins 2t, 2t+1
        unsigned s = v2.x + v2.y;
        sh.sca.part[tid] = s;
        __syncthreads();
        for (int off = 1; off < 1024; off <<= 1) {
            unsigned add = (tid >= off) ? sh.sca.part[tid - off] : 0u;
            __syncthreads();
            sh.sca.part[tid] += add;
            __syncthreads();
        }
        unsigned base = tid ? sh.sca.part[tid - 1] : 0u;
        if (blk == 0) ((uint2*)binStart)[tid] = make_uint2(base, base + v2.x);
        const int b = blk;
        sh.sca.baseB[2 * tid]     = base        + pbh[(size_t)b * NBKT + 2 * tid];
        sh.sca.baseB[2 * tid + 1] = base + v2.x + pbh[(size_t)b * NBKT + 2 * tid + 1];
        sh.sca.lofs[2 * tid] = 0u;
        sh.sca.lofs[2 * tid + 1] = 0u;
        __syncthreads();
        const float* cb = conf + (size_t)b * N_;
        #pragma unroll
        for (int s4 = 0; s4 < 4; ++s4) {
            int n = s4 * 1024 + tid;
            if (n < N_) {
                float c = cb[n];
                unsigned bin = bucket_of(c);
                unsigned lo = atomicAdd(&sh.sca.lofs[bin], 1u);
                unsigned idx = (unsigned)(b * N_ + n);
                sKey[sh.sca.baseB[bin] + lo] =
                    ((u64)__float_as_uint(c) << 32) | (u64)(0xFFFFFFFFu - idx);
            }
        }
    }
    grid.sync();

    // ================= P3: rank — 4096 waves x ~7 slots =================
    {
        const int gw = blk * 16 + wv;
        for (int t = gw; t < 2 * NL_; t += 4096) {
            const int thr_i = t / NL_;
            const int tt = t - thr_i * NL_;
            const int batch = tt / G_;
            const int j = tt - batch * G_;
            if (j < cnt[thr_i * B_ + batch]) {
                int e = tpIdx[thr_i * NL_ + tt];
                float c = conf[e];
                u64 keyE = ((u64)__float_as_uint(c) << 32) | (u64)(0xFFFFFFFFu - (unsigned)e);
                unsigned bin = bucket_of(c);
                unsigned lo = binStart[bin], n = total[bin];
                int r = M_ - (int)lo - (int)n;
                for (unsigned base = 0; base < n; base += 64) {
                    unsigned k = base + lane;
                    bool pred = (k < n) && (sKey[lo + k] > keyE);
                    r += (int)__popcll(__ballot(pred));
                }
                if (lane == 0) tpRank[thr_i * NL_ + tt] = r;
            } else {
                if (lane == 0) tpRank[thr_i * NL_ + tt] = M_ + t % NL_ + thr_i; // distinct sentinels > any rank
            }
        }
    }
    grid.sync();

    // ================= P4: pos1 — 416 tasks (thr,k,xchunk) =================
    {
        for (int task = blk; task < 2 * KP * 13; task += B_) {
            int xb = task % 13;
            int rem = task / 13;
            int k = rem % KP;
            int thr_i = rem / KP;
            const int* baseR = tpRank + thr_i * NL_;
            for (int i = tid; i < TILE; i += 1024)
                sh.pos.tile[i] = baseR[k * TILE + i];
            __syncthreads();
            if (tid < 256) {
                const int t0 = xb * 1024 + tid;
                int r[4], c[4] = {0, 0, 0, 0};
                #pragma unroll
                for (int j = 0; j < 4; ++j) {
                    int t = t0 + j * 256;
                    r[j] = (t < NL_) ? baseR[t] : -1;
                }
                const int4* l4 = (const int4*)sh.pos.tile;
                #pragma unroll 4
                for (int i = 0; i < TILE / 4; ++i) {
                    int4 v = l4[i];
                    #pragma unroll
                    for (int j = 0; j < 4; ++j)
                        c[j] += (v.x < r[j]) + (v.y < r[j]) + (v.z < r[j]) + (v.w < r[j]);
                }
                #pragma unroll
                for (int j = 0; j < 4; ++j) {
                    int t = t0 + j * 256;
                    if (t < NL_) pcount[(thr_i * KP + k) * NL_ + t] = c[j];
                }
            }
            __syncthreads();
        }
    }
    grid.sync();

    // ================= P5: ap (blocks 0,1) =================
    if (blk < 2) {
        const int C = 13;
        const int thr_i = blk;
        const int t = tid;
        #pragma unroll
        for (int j = 0; j < C; ++j) {
            int tt = t + j * 1024;
            if (tt < NL_) {
                int p = 0;
                #pragma unroll
                for (int k = 0; k < KP; ++k)
                    p += pcount[(thr_i * KP + k) * NL_ + tt];
                sh.ap.sr[p] = tpRank[thr_i * NL_ + tt];
            }
        }
        __syncthreads();

        float pr[C]; int rk[C];
        #pragma unroll
        for (int k = 0; k < C; ++k) {
            int i = t * C + k;
            rk[k] = (i < NL_) ? sh.ap.sr[i] : 0x7FFFFFFF;
            pr[k] = (rk[k] < M_) ? (float)(i + 1) / (float)(rk[k] + 1) : -1.0f;
        }
        float suf[C];
        float run = -1.0f;
        #pragma unroll
        for (int k = C - 1; k >= 0; --k) { run = fmaxf(run, pr[k]); suf[k] = run; }

        sh.ap.cmax[t] = run;
        __syncthreads();
        for (int off = 1; off < 1024; off <<= 1) {
            float v = sh.ap.cmax[t];
            float o = (t + off < 1024) ? sh.ap.cmax[t + off] : -1.0f;
            __syncthreads();
            sh.ap.cmax[t] = fmaxf(v, o);
            __syncthreads();
        }
        float follow = (t + 1 < 1024) ? sh.ap.cmax[t + 1] : -1.0f;

        double acc = 0.0;
        #pragma unroll
        for (int k = 0; k < C; ++k) {
            int i = t * C + k;
            if (rk[k] >= 1 && rk[k] < M_) {
                float smax = fmaxf(suf[k], follow);
                float rhi = (float)(i + 1) / 12800.0f;
                float rlo = (float)i / 12800.0f;
                acc += (double)((rhi - rlo) * smax);
            }
        }
        sh.ap.red[t] = acc;
        __syncthreads();
        for (int off = 512; off >= 1; off >>= 1) {
            if (t < off) sh.ap.red[t] += sh.ap.red[t + off];
            __syncthreads();
        }
        if (t == 0) out[thr_i] = (float)sh.ap.red[0];
    }
}

extern "C" void kernel_launch(void* const* d_in, const int* in_sizes, int n_in,
                              void* d_out, int out_size, void* d_ws, size_t ws_size,
                              hipStream_t stream) {
    const float* scores = (const float*)d_in[0];   // [B,N]
    const float* seg    = (const float*)d_in[1];   // [B,N,2]
    const float* gts    = (const float*)d_in[2];   // [B,G,2]
    float* out = (float*)d_out;

    char* p = (char*)d_ws;
    int*            cnt        = (int*)p;             p += 4096;
    int*            tpIdx      = (int*)p;             p += 2 * NL_ * 4;           // 100 KB
    int*            tpRank     = (int*)p;             p += 2 * NL_ * 4;           // 100 KB
    unsigned*       total      = (unsigned*)p;        p += NBKT * 4;              // 8 KB
    unsigned*       binStart   = (unsigned*)p;        p += NBKT * 4;              // 8 KB
    unsigned short* pbh        = (unsigned short*)p;  p += (size_t)B_ * NBKT * 2; // 1 MB
    u64*            sKey       = (u64*)p;             p += (size_t)M_ * 8;        // 8 MB
    int*            pcount     = (int*)sKey;    // aliases sKey (dead after rank)
    (void)ws_size; (void)in_sizes; (void)n_in; (void)out_size;

    void* args[] = {
        (void*)&seg, (void*)&gts, (void*)&scores,
        (void*)&tpIdx, (void*)&cnt, (void*)&pbh,
        (void*)&total, (void*)&binStart,
        (void*)&sKey, (void*)&tpRank, (void*)&pcount, (void*)&out
    };
    hipLaunchCooperativeKernel((const void*)mega_kernel, dim3(B_), dim3(1024),
                               args, 0, stream);
}

// Round 16
// 188.264 us; speedup vs baseline: 1.8817x; 1.8817x over previous
//
#include <hip/hip_runtime.h>

// AP (average precision @ IoU 0.5/0.75) for B=256, N=4000, G=50.
// Strategy: greedy TP matching -> <=50 TPs per (batch,thr); exact stable
// descending-sort ranks of TPs via 2048-bucket counting sort of the 1.024M
// confidences; AP from TP ranks only. Zero global atomics.
//
// R1 pos->LDS 439. R2-R4 tp stuck on 1M global hist atomics -> zero-global-
// atomic counting-sort design. R6 423. R7 rank/wave 260. R8 pos split 204.
// R10 bit-exact divide elimination ((double)i > (thr+2^-25)*(double)u) 191.
// R12/R13 cand->global REGRESSED: at grid==CU-count (256 blocks), 1 block/CU
//   regardless of LDS; LDS<64KB is FREE. R14 NBKT=2048: 187.6 (best).
// R15 cooperative mega-kernel REGRESSED (354us): grid.sync() on 256x1024
//   costs 10s of us each (device fence across 8 XCD L2s) -- fusion only
//   pays within a block.
// R16: R14 base + (a) s2 fused into scatter via per-block redundant bin
//   scan (logic validated in R15 P2), (b) s1 wave-per-bin shuffle scan
//   (barrier-free), (c) KP 16->8 (halves grid-starved ap's pcount reads).

#define B_ 256
#define N_ 4000
#define G_ 50
#define M_ (B_ * N_)        // 1,024,000 proposals total
#define NL_ (B_ * G_)       // 12,800 labels total (= n_labels)
#define NBKT 2048
#define KP 8                // u-tile splits in pos1
#define TILE (NL_ / KP)     // 1600

// exact decision thresholds: thr + 2^-25
#define M0_ 0x1.000001p-1   // 0.5  + 2^-25
#define M1_ 0x1.800001p-1   // 0.75 + 2^-25

typedef unsigned long long u64;

__device__ __forceinline__ unsigned bucket_of(float c) {
    unsigned b = (unsigned)(c * 2048.0f);
    return b > (NBKT - 1) ? (NBKT - 1) : b;
}

// ---- Phase 1: IoU cand masks + greedy (both thr) + LDS histogram. ---------
// One 1024-thread block per batch; grid==256 -> 1 block/CU, LDS is free.
__global__ __launch_bounds__(1024) void tp_kernel(
    const float* __restrict__ seg,    // [B,N,2]
    const float* __restrict__ gts,    // [B,G,2]
    const float* __restrict__ conf,   // [B,N]
    int* __restrict__ tpIdx,          // [2][NL_], slots [b*50, b*50+cnt)
    int* __restrict__ cnt,            // [2][B_]
    unsigned short* __restrict__ pbh) // [B_][NBKT] per-batch histogram
{
    const int tid  = threadIdx.x;
    const int lane = tid & 63;
    const int wv   = tid >> 6;            // wave id 0..15
    const int b    = blockIdx.x;

    __shared__ float2 gtl[G_];            // 400 B
    __shared__ u64 cand[2][G_][64];       // 51.2 KiB
    __shared__ unsigned hls[NBKT];        // 8 KiB
    __shared__ int lcnt[2];               // total 59.8 KiB < 64 KiB

    #pragma unroll
    for (int k = 0; k < NBKT / 1024; ++k) hls[k * 1024 + tid] = 0u;
    if (tid < G_) gtl[tid] = ((const float2*)gts)[b * G_ + tid];
    if (tid < 2) lcnt[tid] = 0;
    __syncthreads();

    // LDS-private histogram of this batch's 4000 scores
    const float* cb = conf + (size_t)b * N_;
    #pragma unroll
    for (int s = 0; s < 4; ++s) {
        int n = s * 1024 + tid;
        if (n < N_) atomicAdd(&hls[bucket_of(cb[n])], 1u);
    }

    // Phase A (g outer, slots inner): props in registers, gt read once per g.
    const float2* sb = (const float2*)(seg + (size_t)b * (N_ * 2));
    float pmin[4], pmax[4], plen[4];
    #pragma unroll
    for (int s = 0; s < 4; ++s) {
        int n = s * 1024 + tid;
        if (n < N_) { float2 v = sb[n]; pmin[s] = v.x; pmax[s] = v.y; }
        else { pmin[s] = 1e9f; pmax[s] = 1e9f; }   // sentinel -> iou 0
        plen[s] = pmax[s] - pmin[s];               // == ref's (amax - amin)
    }
    for (int g = 0; g < G_; ++g) {
        float2 gt = gtl[g];                        // one LDS broadcast per g
        float glen = gt.y - gt.x;
        u64 m0[4], m1[4];
        #pragma unroll
        for (int s = 0; s < 4; ++s) {
            float inter = fmaxf(fminf(pmax[s], gt.y) - fmaxf(pmin[s], gt.x), 0.0f);
            float uni = plen[s] + glen - inter;    // f32, same op order as ref
            double di = (double)inter;             // exact
            double du = (double)uni;               // exact; uni > 0 always
            m0[s] = __ballot(di > M0_ * du);       // == fl(inter/uni) > 0.5f
            m1[s] = __ballot(di > M1_ * du);       // == fl(inter/uni) > 0.75f
        }
        if (lane == 0) {                           // one branch, 8 LDS stores
            #pragma unroll
            for (int s = 0; s < 4; ++s) {
                cand[0][g][s * 16 + wv] = m0[s];
                cand[1][g][s * 16 + wv] = m1[s];
            }
        }
    }
    __syncthreads();   // cand complete + hist complete

    // write per-batch histogram row (u16; per-batch bin count <= 4000)
    #pragma unroll
    for (int k = 0; k < NBKT / 1024; ++k) {
        int bin = k * 1024 + tid;
        pbh[(size_t)b * NBKT + bin] = (unsigned short)hls[bin];
    }

    // Phase B: wave 0 -> thr 0.5, wave 1 -> thr 0.75. Greedy via ballot+ffs.
    if (wv < 2) {
        const int thr_i = wv;
        u64 used = 0ull;                     // proposals [lane*64, lane*64+64)
        for (int g = 0; g < G_; ++g) {
            u64 c = cand[thr_i][g][lane] & ~used;
            u64 ball = __ballot(c != 0ull);
            if (ball) {
                int fl = __ffsll(ball) - 1;  // lowest lane = lowest proposal range
                if (lane == fl) used |= (c & (0ull - c));   // lowest set bit
            }
        }
        int cpop = __popcll(used);
        if (cpop) {
            int j = atomicAdd(&lcnt[thr_i], cpop);   // LDS atomic, block-local
            u64 u = used;
            while (u) {
                int bit = __ffsll(u) - 1;
                u &= u - 1;
                tpIdx[thr_i * NL_ + b * G_ + j++] = b * N_ + lane * 64 + bit;
            }
        }
    }
    __syncthreads();
    if (tid < 2) cnt[tid * B_ + b] = lcnt[tid];
}

// ---- S1: one WAVE per bin; barrier-free shuffle scan over 256 batches -----
__global__ __launch_bounds__(256) void s1_kernel(
    unsigned short* __restrict__ pbh,        // [B_][NBKT] -> becomes prefix
    unsigned* __restrict__ total)            // [NBKT]
{
    const int lane = threadIdx.x & 63;
    const int bin = blockIdx.x * 4 + (threadIdx.x >> 6);
    unsigned v[4], loc[4], s = 0;
    #pragma unroll
    for (int i = 0; i < 4; ++i) {            // batches lane*4 .. lane*4+3
        v[i] = pbh[(size_t)(lane * 4 + i) * NBKT + bin];
        loc[i] = s; s += v[i];
    }
    unsigned x = s;                          // inclusive wave scan of s
    #pragma unroll
    for (int off = 1; off < 64; off <<= 1) {
        unsigned t = __shfl_up(x, off, 64);
        if (lane >= off) x += t;
    }
    unsigned excl = x - s;
    #pragma unroll
    for (int i = 0; i < 4; ++i)
        pbh[(size_t)(lane * 4 + i) * NBKT + bin] = (unsigned short)(excl + loc[i]);
    if (lane == 63) total[bin] = x;
}

// ---- Scatter (+fused s2): per-block redundant scan of 2048 bin totals. ----
// key = bits(conf)<<32 | ~idx : u64 ordering == (conf desc, idx asc) exactly.
__global__ __launch_bounds__(1024) void scatter_kernel(
    const float* __restrict__ conf,
    const unsigned short* __restrict__ pbh,  // exclusive prefix per (b,bin)
    const unsigned* __restrict__ total,
    unsigned* __restrict__ binStart,         // written by block 0 (for rank)
    u64* __restrict__ sKey)
{
    __shared__ unsigned part[1024];    // 4 KiB
    __shared__ unsigned baseB[NBKT];   // 8 KiB
    __shared__ unsigned lofs[NBKT];    // 8 KiB
    const int tid = threadIdx.x;
    const int b = blockIdx.x;

    uint2 v2 = ((const uint2*)total)[tid];       // bins 2t, 2t+1
    unsigned s = v2.x + v2.y;
    part[tid] = s;
    __syncthreads();
    for (int off = 1; off < 1024; off <<= 1) {   // inclusive Hillis-Steele
        unsigned add = (tid >= off) ? part[tid - off] : 0u;
        __syncthreads();
        part[tid] += add;
        __syncthreads();
    }
    unsigned base = tid ? part[tid - 1] : 0u;
    if (b == 0) ((uint2*)binStart)[tid] = make_uint2(base, base + v2.x);
    baseB[2 * tid]     = base        + pbh[(size_t)b * NBKT + 2 * tid];
    baseB[2 * tid + 1] = base + v2.x + pbh[(size_t)b * NBKT + 2 * tid + 1];
    lofs[2 * tid] = 0u;
    lofs[2 * tid + 1] = 0u;
    __syncthreads();

    const float* cb = conf + (size_t)b * N_;
    #pragma unroll
    for (int s4 = 0; s4 < 4; ++s4) {
        int n = s4 * 1024 + tid;
        if (n < N_) {
            float c = cb[n];
            unsigned bin = bucket_of(c);
            unsigned lo = atomicAdd(&lofs[bin], 1u);   // LDS atomic
            unsigned idx = (unsigned)(b * N_ + n);
            sKey[baseB[bin] + lo] = ((u64)__float_as_uint(c) << 32) | (u64)(0xFFFFFFFFu - idx);
        }
    }
}

// ---- Rank: one WAVE per TP slot; lanes stride the ~500-elem bucket --------
__global__ __launch_bounds__(256) void rank_kernel(
    const float* __restrict__ conf,
    const int* __restrict__ tpIdx,
    const int* __restrict__ cnt,
    const unsigned* __restrict__ total,
    const unsigned* __restrict__ binStart,
    const u64* __restrict__ sKey,
    int* __restrict__ tpRank)
{
    const int lane = threadIdx.x & 63;
    const int w = (blockIdx.x << 2) | (threadIdx.x >> 6);   // global wave id
    if (w >= 2 * NL_) return;
    const int thr_i = w / NL_;
    const int t = w - thr_i * NL_;
    const int batch = t / G_;
    const int j = t - batch * G_;

    if (j < cnt[thr_i * B_ + batch]) {
        int e = tpIdx[thr_i * NL_ + t];
        float c = conf[e];
        u64 keyE = ((u64)__float_as_uint(c) << 32) | (u64)(0xFFFFFFFFu - (unsigned)e);
        unsigned bin = bucket_of(c);
        unsigned lo = binStart[bin], n = total[bin];
        int r = M_ - (int)lo - (int)n;   // strictly-better buckets
        for (unsigned base = 0; base < n; base += 64) {
            unsigned k = base + lane;
            bool pred = (k < n) && (sKey[lo + k] > keyE);
            r += (int)__popcll(__ballot(pred));   // wave-uniform partial sum
        }
        if (lane == 0) tpRank[thr_i * NL_ + t] = r;
    } else {
        if (lane == 0) tpRank[thr_i * NL_ + t] = M_ + t;   // distinct sentinel
    }
}

// ---- Pos1: partial counts, 4 t's per lane, K=8 u-tiles --------------------
__global__ __launch_bounds__(256) void pos1_kernel(
    const int* __restrict__ tpRank,
    int* __restrict__ pcount)          // [2][KP][NL_]
{
    __shared__ alignas(16) int tile[TILE];
    const int k = blockIdx.y, thr_i = blockIdx.z;
    const int* base = tpRank + thr_i * NL_;
    for (int i = threadIdx.x; i < TILE; i += 256)
        tile[i] = base[k * TILE + i];
    __syncthreads();

    const int t0 = blockIdx.x * 1024 + threadIdx.x;
    int r[4], c[4] = {0, 0, 0, 0};
    #pragma unroll
    for (int j = 0; j < 4; ++j) {
        int t = t0 + j * 256;
        r[j] = (t < NL_) ? base[t] : -1;   // ranks >= 0, so c stays 0
    }
    const int4* l4 = (const int4*)tile;
    #pragma unroll 4
    for (int i = 0; i < TILE / 4; ++i) {   // wave-uniform -> LDS broadcast
        int4 v = l4[i];
        #pragma unroll
        for (int j = 0; j < 4; ++j)
            c[j] += (v.x < r[j]) + (v.y < r[j]) + (v.z < r[j]) + (v.w < r[j]);
    }
    #pragma unroll
    for (int j = 0; j < 4; ++j) {
        int t = t0 + j * 256;
        if (t < NL_) pcount[(thr_i * KP + k) * NL_ + t] = c[j];
    }
}

// ---- AP (fused pos2): sum partials -> LDS scatter -> AP. One block/thr. ---
__global__ __launch_bounds__(1024) void ap_kernel(
    const int* __restrict__ tpRank,
    const int* __restrict__ pcount,
    float* __restrict__ out)
{
    const int C = 13;   // 1024*13 = 13312 >= NL_
    __shared__ int sr[NL_];            // 51.2 KiB
    __shared__ float cmax[1024];       // 4 KiB
    __shared__ double red[1024];       // 8 KiB  -> 63.5 KiB total
    int thr_i = blockIdx.x;
    int t = threadIdx.x;

    // pos2 inlined: p = sum of 8 partials; scatter rank into sorted LDS slot
    #pragma unroll
    for (int j = 0; j < C; ++j) {
        int tt = t + j * 1024;         // coalesced
        if (tt < NL_) {
            int p = 0;
            #pragma unroll
            for (int k = 0; k < KP; ++k)
                p += pcount[(thr_i * KP + k) * NL_ + tt];
            sr[p] = tpRank[thr_i * NL_ + tt];   // bijection: every slot written
        }
    }
    __syncthreads();

    float pr[C]; int rk[C];
    #pragma unroll
    for (int k = 0; k < C; ++k) {
        int i = t * C + k;
        rk[k] = (i < NL_) ? sr[i] : 0x7FFFFFFF;
        pr[k] = (rk[k] < M_) ? (float)(i + 1) / (float)(rk[k] + 1) : -1.0f;
    }
    float suf[C];
    float run = -1.0f;
    #pragma unroll
    for (int k = C - 1; k >= 0; --k) { run = fmaxf(run, pr[k]); suf[k] = run; }

    cmax[t] = run;
    __syncthreads();
    for (int off = 1; off < 1024; off <<= 1) {   // inclusive suffix-max scan
        float v = cmax[t];
        float o = (t + off < 1024) ? cmax[t + off] : -1.0f;
        __syncthreads();
        cmax[t] = fmaxf(v, o);
        __syncthreads();
    }
    float follow = (t + 1 < 1024) ? cmax[t + 1] : -1.0f;

    double acc = 0.0;
    #pragma unroll
    for (int k = 0; k < C; ++k) {
        int i = t * C + k;
        if (rk[k] >= 1 && rk[k] < M_) {   // global rank 0 excluded by ref curve
            float smax = fmaxf(suf[k], follow);
            float rhi = (float)(i + 1) / 12800.0f;
            float rlo = (float)i / 12800.0f;
            acc += (double)((rhi - rlo) * smax);
        }
    }
    red[t] = acc;
    __syncthreads();
    for (int off = 512; off >= 1; off >>= 1) {
        if (t < off) red[t] += red[t + off];
        __syncthreads();
    }
    if (t == 0) out[thr_i] = (float)red[0];
}

extern "C" void kernel_launch(void* const* d_in, const int* in_sizes, int n_in,
                              void* d_out, int out_size, void* d_ws, size_t ws_size,
                              hipStream_t stream) {
    const float* scores = (const float*)d_in[0];   // [B,N]
    const float* seg    = (const float*)d_in[1];   // [B,N,2]
    const float* gts    = (const float*)d_in[2];   // [B,G,2]
    float* out = (float*)d_out;

    char* p = (char*)d_ws;
    int*            cnt        = (int*)p;             p += 4096;                  // 2KB used
    int*            tpIdx      = (int*)p;             p += 2 * NL_ * 4;           // 100 KB
    int*            tpRank     = (int*)p;             p += 2 * NL_ * 4;           // 100 KB
    unsigned*       total      = (unsigned*)p;        p += NBKT * 4;              // 8 KB
    unsigned*       binStart   = (unsigned*)p;        p += NBKT * 4;              // 8 KB
    unsigned short* pbh        = (unsigned short*)p;  p += (size_t)B_ * NBKT * 2; // 1 MB
    u64*            sKey       = (u64*)p;             p += (size_t)M_ * 8;        // 8 MB
    int*            pcount     = (int*)sKey;    // aliases sKey (dead after rank)
    (void)ws_size; (void)in_sizes; (void)n_in; (void)out_size;

    // No memset: every workspace word read downstream is written upstream.
    tp_kernel<<<B_, 1024, 0, stream>>>(seg, gts, scores, tpIdx, cnt, pbh);
    s1_kernel<<<NBKT / 4, 256, 0, stream>>>(pbh, total);
    scatter_kernel<<<B_, 1024, 0, stream>>>(scores, pbh, total, binStart, sKey);
    rank_kernel<<<(2 * NL_ + 3) / 4, 256, 0, stream>>>(scores, tpIdx, cnt,
                                                       total, binStart, sKey, tpRank);
    pos1_kernel<<<dim3(13, KP, 2), 256, 0, stream>>>(tpRank, pcount);
    ap_kernel<<<2, 1024, 0, stream>>>(tpRank, pcount, out);
}